// Round 1
// baseline (605.709 us; speedup 1.0000x reference)
//
#include <hip/hip_runtime.h>
#include <cstdint>

#define HWN 1024      // H*W
#define CDIM 256      // channels
#define KCODES 2048   // codebook size
#define NBATCH 32
#define MROWS (NBATCH*HWN)   // 32768

#define TM 32         // rows per block
#define TK 256        // codes per k-tile
#define CCH 32        // channels per chunk
#define NKT (KCODES/TK)   // 8
#define NCH (CDIM/CCH)    // 8

// ---------------- kernel 1: e2[k] = sum_c E[k][c]^2 -------------------------
__global__ __launch_bounds__(256) void e2_kernel(const float* __restrict__ E,
                                                 float* __restrict__ e2) {
  int gt = blockIdx.x * 256 + threadIdx.x;
  int wave = gt >> 6;                    // one wave per code
  int lane = threadIdx.x & 63;
  if (wave >= KCODES) return;
  const float4 v = reinterpret_cast<const float4*>(E + (size_t)wave * CDIM)[lane];
  float s = v.x*v.x + v.y*v.y + v.z*v.z + v.w*v.w;
  #pragma unroll
  for (int off = 32; off > 0; off >>= 1) s += __shfl_down(s, off);
  if (lane == 0) e2[wave] = s;
}

// ---------------- kernel 2: fp32 distance GEMM + row argmin ------------------
// block: 256 threads = 8 row-groups (4 rows each) x 32 code-groups (8 codes each)
__global__ __launch_bounds__(256, 2) void dist_kernel(
    const float* __restrict__ X,   // latent [B, C, H, W]
    const float* __restrict__ E,   // [K, C]
    const float* __restrict__ e2,  // [K]
    int* __restrict__ out_idx)     // [M]
{
  __shared__ float xs[CDIM * TM];   // [c][row]  32 KB, transposed at stage time
  __shared__ float es[CCH * TK];    // [cc][k^swz] 32 KB

  const int tid = threadIdx.x;
  const int blk = blockIdx.x;
  const int b   = blk >> 5;              // 32 n-tiles per batch
  const int n0  = (blk & 31) * TM;
  const int tr  = tid >> 5;              // 0..7 row group
  const int tc  = tid & 31;              // 0..31 code group

  // ---- stage X tile once: xs[c][j]; writes conflict-free (bank = j) ----
  {
    const float* xbase = X + ((size_t)b * CDIM) * HWN + n0;
    int j = tid & 31;
    int csub = tid >> 5;
    #pragma unroll
    for (int it = 0; it < 32; ++it) {
      int c = it * 8 + csub;
      xs[c * TM + j] = xbase[(size_t)c * HWN + j];
    }
  }

  float vmin[4];
  int   vidx[4];
  #pragma unroll
  for (int i = 0; i < 4; ++i) { vmin[i] = 3.4e38f; vidx[i] = 0; }

  const int kb0 = 8 * tc;             // thread's code base within k-tile
  const int kb1 = 8 * tc + 4;
  const int sw0 = (kb0 >> 5) & 3;     // swizzle high bits (same for kb1)

  for (int kt = 0; kt < NKT; ++kt) {
    const int k0 = kt * TK;
    float acc[4][8];
    #pragma unroll
    for (int i = 0; i < 4; ++i)
      #pragma unroll
      for (int j = 0; j < 8; ++j) acc[i][j] = 0.f;

    for (int ch = 0; ch < NCH; ++ch) {
      const int c0 = ch * CCH;
      // ---- stage E chunk: coalesced float4 global reads, swizzled LDS writes
      {
        int klo = tid >> 3;            // 0..31
        int c4  = 4 * (tid & 7);       // 0,4,...,28
        #pragma unroll
        for (int it = 0; it < 8; ++it) {
          int kl = it * 32 + klo;      // 0..255
          float4 v = *reinterpret_cast<const float4*>(
              E + (size_t)(k0 + kl) * CDIM + c0 + c4);
          float vv[4] = {v.x, v.y, v.z, v.w};
          int khi = (kl >> 5) & 3;
          #pragma unroll
          for (int i = 0; i < 4; ++i) {
            int cc = c4 + i;
            int k2 = kl ^ (((khi ^ (cc & 7)) & 7) << 2);
            es[cc * TK + k2] = vv[i];
          }
        }
      }
      __syncthreads();
      // ---- compute: 32 fma per c-step per thread (VALU-bound)
      #pragma unroll 8
      for (int cc = 0; cc < CCH; ++cc) {
        const int sw = ((sw0 ^ (cc & 7)) & 7) << 2;
        const float4 xv = *reinterpret_cast<const float4*>(
            &xs[(c0 + cc) * TM + 4 * tr]);                 // broadcast b128
        const float4 ea = *reinterpret_cast<const float4*>(
            &es[cc * TK + (kb0 ^ sw)]);
        const float4 eb = *reinterpret_cast<const float4*>(
            &es[cc * TK + (kb1 ^ sw)]);
        const float xr[4] = {xv.x, xv.y, xv.z, xv.w};
        const float er[8] = {ea.x, ea.y, ea.z, ea.w, eb.x, eb.y, eb.z, eb.w};
        #pragma unroll
        for (int i = 0; i < 4; ++i)
          #pragma unroll
          for (int j = 0; j < 8; ++j)
            acc[i][j] = fmaf(xr[i], er[j], acc[i][j]);
      }
      __syncthreads();
    }

    // ---- epilogue: s = e2[k] - 2*dot ; running (min, argmin), k ascending
    const float4 ea = *reinterpret_cast<const float4*>(e2 + k0 + kb0);
    const float4 eb = *reinterpret_cast<const float4*>(e2 + k0 + kb1);
    const float e2r[8] = {ea.x, ea.y, ea.z, ea.w, eb.x, eb.y, eb.z, eb.w};
    #pragma unroll
    for (int i = 0; i < 4; ++i) {
      #pragma unroll
      for (int j = 0; j < 8; ++j) {
        float s = fmaf(-2.f, acc[i][j], e2r[j]);
        int code = k0 + kb0 + j;
        if (s < vmin[i]) { vmin[i] = s; vidx[i] = code; }
      }
    }
  }

  // ---- cross-thread reduce per row (reuse es; safe after last barrier) ----
  float* red_min = es;                  // 1024 floats
  int*   red_idx = (int*)(es + 1024);   // 1024 ints
  #pragma unroll
  for (int i = 0; i < 4; ++i) {
    int r = 4 * tr + i;
    red_min[r * 32 + tc] = vmin[i];
    red_idx[r * 32 + tc] = vidx[i];
  }
  __syncthreads();
  if (tid < TM) {
    float best = 3.4e38f; int bi = 0x7fffffff;
    for (int q = 0; q < 32; ++q) {
      float v = red_min[tid * 32 + q];
      int  id = red_idx[tid * 32 + q];
      // lexicographic (value, index): matches numpy first-min semantics
      if (v < best || (v == best && id < bi)) { best = v; bi = id; }
    }
    out_idx[blk * TM + tid] = bi;
  }
}

// ---------------- kernel 3: gather codebook rows + MSE partials --------------
__global__ __launch_bounds__(256) void out_kernel(
    const float* __restrict__ X, const float* __restrict__ E,
    const int* __restrict__ idx, float* __restrict__ out,
    float* __restrict__ partial)
{
  __shared__ float warpsum[4];
  size_t t = (size_t)blockIdx.x * 256 + threadIdx.x;
  size_t base = t * 8;
  float lsum = 0.f;
  #pragma unroll
  for (int g = 0; g < 2; ++g) {
    size_t e0 = base + (size_t)g * 4;
    int b = (int)(e0 >> 18);           // / (256*1024)
    int c = (int)((e0 >> 10) & 255);
    int n = (int)(e0 & 1023);
    const int4 iv = *reinterpret_cast<const int4*>(idx + b * HWN + n);
    float4 q;
    q.x = E[(size_t)iv.x * CDIM + c];
    q.y = E[(size_t)iv.y * CDIM + c];
    q.z = E[(size_t)iv.z * CDIM + c];
    q.w = E[(size_t)iv.w * CDIM + c];
    const float4 xv = *reinterpret_cast<const float4*>(X + e0);
    *reinterpret_cast<float4*>(out + e0) = q;
    float dx = xv.x - q.x, dy = xv.y - q.y, dz = xv.z - q.z, dw = xv.w - q.w;
    lsum += dx*dx + dy*dy + dz*dz + dw*dw;
  }
  #pragma unroll
  for (int off = 32; off > 0; off >>= 1) lsum += __shfl_down(lsum, off);
  int lane = threadIdx.x & 63, wv = threadIdx.x >> 6;
  if (lane == 0) warpsum[wv] = lsum;
  __syncthreads();
  if (threadIdx.x == 0)
    partial[blockIdx.x] = warpsum[0] + warpsum[1] + warpsum[2] + warpsum[3];
}

// ---------------- kernel 4: deterministic final loss reduce ------------------
__global__ __launch_bounds__(256) void loss_kernel(const float* __restrict__ partial,
                                                   float* __restrict__ out_loss) {
  __shared__ double sd[256];
  double s = 0.0;
  for (int i = threadIdx.x; i < 4096; i += 256) s += (double)partial[i];
  sd[threadIdx.x] = s;
  __syncthreads();
  if (threadIdx.x == 0) {
    double tot = 0.0;
    for (int i = 0; i < 256; ++i) tot += sd[i];
    out_loss[0] = (float)(tot / 8388608.0);
  }
}

extern "C" void kernel_launch(void* const* d_in, const int* in_sizes, int n_in,
                              void* d_out, int out_size, void* d_ws, size_t ws_size,
                              hipStream_t stream) {
  const float* X = (const float*)d_in[0];   // [32,256,32,32] fp32
  const float* E = (const float*)d_in[1];   // [2048,256] fp32
  float* out = (float*)d_out;               // 8388608 quantized + 1 loss

  float* e2      = (float*)d_ws;                             // 2048 f
  int*   idx     = (int*)((char*)d_ws + 8192);               // 32768 i
  float* partial = (float*)((char*)d_ws + 8192 + 131072);    // 4096 f

  e2_kernel  <<<512,  256, 0, stream>>>(E, e2);
  dist_kernel<<<1024, 256, 0, stream>>>(X, E, e2, idx);
  out_kernel <<<4096, 256, 0, stream>>>(X, E, idx, out, partial);
  loss_kernel<<<1,    256, 0, stream>>>(partial, out + 8388608);
}

// Round 2
// 597.132 us; speedup vs baseline: 1.0144x; 1.0144x over previous
//
#include <hip/hip_runtime.h>
#include <cstdint>

#define HWN 1024      // H*W
#define CDIM 256      // channels
#define KCODES 2048   // codebook size
#define NBATCH 32
#define MROWS (NBATCH*HWN)   // 32768

#define TM 32         // rows per block
#define TK 256        // codes per k-tile
#define CCH 16        // channels per chunk (16 KB es -> 48 KB total -> 3 blocks/CU)
#define NKT (KCODES/TK)   // 8
#define NCH (CDIM/CCH)    // 16

// ---------------- kernel 1: e2[k] = sum_c E[k][c]^2 -------------------------
__global__ __launch_bounds__(256) void e2_kernel(const float* __restrict__ E,
                                                 float* __restrict__ e2) {
  int gt = blockIdx.x * 256 + threadIdx.x;
  int wave = gt >> 6;                    // one wave per code
  int lane = threadIdx.x & 63;
  if (wave >= KCODES) return;
  const float4 v = reinterpret_cast<const float4*>(E + (size_t)wave * CDIM)[lane];
  float s = v.x*v.x + v.y*v.y + v.z*v.z + v.w*v.w;
  #pragma unroll
  for (int off = 32; off > 0; off >>= 1) s += __shfl_down(s, off);
  if (lane == 0) e2[wave] = s;
}

// ---------------- kernel 2: fp32 distance GEMM + row argmin ------------------
// block: 256 threads = 8 row-groups (4 rows each) x 32 code-groups (8 codes each)
// es swizzle: word (cc,k) stored at cc*TK + (k ^ ((((k>>5)^cc)&7)<<2)).
//  - invertible (XOR only touches bits 2-4, controlled by bits >=5 and cc)
//  - read kb0=8*tc: quad index = [t1^t4^c2, t0^t3^c1, t2^c0] -> each group of
//    8 consecutive lanes covers all 8 bank-quads -> conflict-free b128 reads.
__global__ __launch_bounds__(256, 3) void dist_kernel(
    const float* __restrict__ X,   // latent [B, C, H, W]
    const float* __restrict__ E,   // [K, C]
    const float* __restrict__ e2,  // [K]
    int* __restrict__ out_idx)     // [M]
{
  __shared__ float xs[CDIM * TM];   // [c][row]  32 KB, transposed at stage time
  __shared__ float es[CCH * TK];    // [cc][k^swz] 16 KB

  const int tid = threadIdx.x;
  const int blk = blockIdx.x;
  const int b   = blk >> 5;              // 32 n-tiles per batch
  const int n0  = (blk & 31) * TM;
  const int tr  = tid >> 5;              // 0..7 row group
  const int tc  = tid & 31;              // 0..31 code group

  // ---- stage X tile once: xs[c][j]; bank = j -> 2-way (free) ----
  {
    const float* xbase = X + ((size_t)b * CDIM) * HWN + n0;
    int j = tid & 31;
    int csub = tid >> 5;
    #pragma unroll
    for (int it = 0; it < 32; ++it) {
      int c = it * 8 + csub;
      xs[c * TM + j] = xbase[(size_t)c * HWN + j];
    }
  }

  float vmin[4];
  int   vidx[4];
  #pragma unroll
  for (int i = 0; i < 4; ++i) { vmin[i] = 3.4e38f; vidx[i] = 0; }

  const int kb0 = 8 * tc;             // thread's code base within k-tile
  const int khr = tc >> 2;            // kb0>>5 (same for kb0 and kb0+4)

  for (int kt = 0; kt < NKT; ++kt) {
    const int k0 = kt * TK;
    float acc[4][8];
    #pragma unroll
    for (int i = 0; i < 4; ++i)
      #pragma unroll
      for (int j = 0; j < 8; ++j) acc[i][j] = 0.f;

    for (int ch = 0; ch < NCH; ++ch) {
      const int c0 = ch * CCH;
      // ---- stage E chunk: coalesced float4 global reads, swizzled LDS writes
      {
        int klo = tid >> 2;            // 0..63
        int c4  = 4 * (tid & 3);       // 0,4,8,12
        #pragma unroll
        for (int it = 0; it < 4; ++it) {
          int kl = it * 64 + klo;      // 0..255
          float4 v = *reinterpret_cast<const float4*>(
              E + (size_t)(k0 + kl) * CDIM + c0 + c4);
          float vv[4] = {v.x, v.y, v.z, v.w};
          int khi = kl >> 5;
          #pragma unroll
          for (int i = 0; i < 4; ++i) {
            int cc = c4 + i;
            int k2 = kl ^ (((khi ^ cc) & 7) << 2);
            es[cc * TK + k2] = vv[i];
          }
        }
      }
      __syncthreads();
      // ---- compute: 32 fma per c-step per thread (VALU-bound)
      #pragma unroll 8
      for (int cc = 0; cc < CCH; ++cc) {
        const int sw = ((khr ^ cc) & 7) << 2;
        const float4 xv = *reinterpret_cast<const float4*>(
            &xs[(c0 + cc) * TM + 4 * tr]);                 // broadcast b128
        const float4 ea = *reinterpret_cast<const float4*>(
            &es[cc * TK + (kb0 ^ sw)]);
        const float4 eb = *reinterpret_cast<const float4*>(
            &es[cc * TK + ((kb0 + 4) ^ sw)]);
        const float xr[4] = {xv.x, xv.y, xv.z, xv.w};
        const float er[8] = {ea.x, ea.y, ea.z, ea.w, eb.x, eb.y, eb.z, eb.w};
        #pragma unroll
        for (int i = 0; i < 4; ++i)
          #pragma unroll
          for (int j = 0; j < 8; ++j)
            acc[i][j] = fmaf(xr[i], er[j], acc[i][j]);
      }
      __syncthreads();
    }

    // ---- epilogue: s = e2[k] - 2*dot ; running (min, argmin), k ascending
    const float4 ea = *reinterpret_cast<const float4*>(e2 + k0 + kb0);
    const float4 eb = *reinterpret_cast<const float4*>(e2 + k0 + kb0 + 4);
    const float e2r[8] = {ea.x, ea.y, ea.z, ea.w, eb.x, eb.y, eb.z, eb.w};
    #pragma unroll
    for (int i = 0; i < 4; ++i) {
      #pragma unroll
      for (int j = 0; j < 8; ++j) {
        float s = fmaf(-2.f, acc[i][j], e2r[j]);
        int code = k0 + kb0 + j;
        if (s < vmin[i]) { vmin[i] = s; vidx[i] = code; }
      }
    }
  }

  // ---- cross-thread reduce per row (reuse es; safe after last barrier) ----
  float* red_min = es;                  // 1024 floats
  int*   red_idx = (int*)(es + 1024);   // 1024 ints
  #pragma unroll
  for (int i = 0; i < 4; ++i) {
    int r = 4 * tr + i;
    red_min[r * 32 + tc] = vmin[i];
    red_idx[r * 32 + tc] = vidx[i];
  }
  __syncthreads();
  if (tid < TM) {
    float best = 3.4e38f; int bi = 0x7fffffff;
    for (int q = 0; q < 32; ++q) {
      float v = red_min[tid * 32 + q];
      int  id = red_idx[tid * 32 + q];
      // lexicographic (value, index): matches numpy first-min semantics
      if (v < best || (v == best && id < bi)) { best = v; bi = id; }
    }
    out_idx[blk * TM + tid] = bi;
  }
}

// ---------------- kernel 3: gather codebook rows + MSE partials --------------
__global__ __launch_bounds__(256) void out_kernel(
    const float* __restrict__ X, const float* __restrict__ E,
    const int* __restrict__ idx, float* __restrict__ out,
    float* __restrict__ partial)
{
  __shared__ float warpsum[4];
  size_t t = (size_t)blockIdx.x * 256 + threadIdx.x;
  size_t base = t * 8;
  float lsum = 0.f;
  #pragma unroll
  for (int g = 0; g < 2; ++g) {
    size_t e0 = base + (size_t)g * 4;
    int b = (int)(e0 >> 18);           // / (256*1024)
    int c = (int)((e0 >> 10) & 255);
    int n = (int)(e0 & 1023);
    const int4 iv = *reinterpret_cast<const int4*>(idx + b * HWN + n);
    float4 q;
    q.x = E[(size_t)iv.x * CDIM + c];
    q.y = E[(size_t)iv.y * CDIM + c];
    q.z = E[(size_t)iv.z * CDIM + c];
    q.w = E[(size_t)iv.w * CDIM + c];
    const float4 xv = *reinterpret_cast<const float4*>(X + e0);
    *reinterpret_cast<float4*>(out + e0) = q;
    float dx = xv.x - q.x, dy = xv.y - q.y, dz = xv.z - q.z, dw = xv.w - q.w;
    lsum += dx*dx + dy*dy + dz*dz + dw*dw;
  }
  #pragma unroll
  for (int off = 32; off > 0; off >>= 1) lsum += __shfl_down(lsum, off);
  int lane = threadIdx.x & 63, wv = threadIdx.x >> 6;
  if (lane == 0) warpsum[wv] = lsum;
  __syncthreads();
  if (threadIdx.x == 0)
    partial[blockIdx.x] = warpsum[0] + warpsum[1] + warpsum[2] + warpsum[3];
}

// ---------------- kernel 4: deterministic final loss reduce ------------------
__global__ __launch_bounds__(256) void loss_kernel(const float* __restrict__ partial,
                                                   float* __restrict__ out_loss) {
  __shared__ double sd[256];
  double s = 0.0;
  for (int i = threadIdx.x; i < 4096; i += 256) s += (double)partial[i];
  sd[threadIdx.x] = s;
  __syncthreads();
  if (threadIdx.x == 0) {
    double tot = 0.0;
    for (int i = 0; i < 256; ++i) tot += sd[i];
    out_loss[0] = (float)(tot / 8388608.0);
  }
}

extern "C" void kernel_launch(void* const* d_in, const int* in_sizes, int n_in,
                              void* d_out, int out_size, void* d_ws, size_t ws_size,
                              hipStream_t stream) {
  const float* X = (const float*)d_in[0];   // [32,256,32,32] fp32
  const float* E = (const float*)d_in[1];   // [2048,256] fp32
  float* out = (float*)d_out;               // 8388608 quantized + 1 loss

  float* e2      = (float*)d_ws;                             // 2048 f
  int*   idx     = (int*)((char*)d_ws + 8192);               // 32768 i
  float* partial = (float*)((char*)d_ws + 8192 + 131072);    // 4096 f

  e2_kernel  <<<512,  256, 0, stream>>>(E, e2);
  dist_kernel<<<1024, 256, 0, stream>>>(X, E, e2, idx);
  out_kernel <<<4096, 256, 0, stream>>>(X, E, idx, out, partial);
  loss_kernel<<<1,    256, 0, stream>>>(partial, out + 8388608);
}